// Round 8
// baseline (193.352 us; speedup 1.0000x reference)
//
#include <hip/hip_runtime.h>

// CTC batch cost — R8: 2-wave split (fwd | bwd) + 1 divergent load per
// iteration per chain + inline-asm double-buffered load pipeline with
// counted s_waitcnt vmcnt(8) (T3/T4 idiom) so the compiler cannot collapse
// the prefetch (observed: R2/R7 both showed fully-serialized load latency,
// ~378 cy per load on the serial chain).
//
//   Wave 0: forward  alpha chain, t = 1..127   (127 steps, rows 1..127)
//   Wave 1: backward beta  chain, t = 255..128 (128 steps, rows 255..128)
//   Combine via 1 KB LDS + one __syncthreads at the end.
//
// Backward "next-slot" operand eliminated: vtn[i] == vta[i+1] (DPP shl1,
// lane32 patched with readfirstlane, lane31 masked, lane63 dead) — saves a
// divergent load per iteration, bit-identically.
// All f32 pre-scale ((p+EPS)*128) and f64 op order identical to the
// verified kernel (absmax = 0.0 preserved).
// B=1024, T=256, C=128, L=32, S=65, blank=127.

#define CTC_B 1024
#define CTC_T 256
#define CTC_C 128
#define CTC_L 32
#define CTC_BLANK 127
#define CTC_EPS 1e-7f

#define DPP_WAVE_SHL1 0x130  // lane i <- lane i+1, lane 63 <- 0 (bound_ctrl)
#define DPP_WAVE_SHR1 0x138  // lane i <- lane i-1, lane 0  <- 0 (bound_ctrl)

__device__ __forceinline__ double dpp_shr1_f64(double v) {
    union { double d; int i[2]; } u; u.d = v;
    int x = __builtin_amdgcn_update_dpp(0, u.i[0], DPP_WAVE_SHR1, 0xF, 0xF, true);
    int y = __builtin_amdgcn_update_dpp(0, u.i[1], DPP_WAVE_SHR1, 0xF, 0xF, true);
    union { int i[2]; double d; } r; r.i[0] = x; r.i[1] = y;
    return r.d;
}

__device__ __forceinline__ double dpp_shl1_f64(double v) {
    union { double d; int i[2]; } u; u.d = v;
    int x = __builtin_amdgcn_update_dpp(0, u.i[0], DPP_WAVE_SHL1, 0xF, 0xF, true);
    int y = __builtin_amdgcn_update_dpp(0, u.i[1], DPP_WAVE_SHL1, 0xF, 0xF, true);
    union { int i[2]; double d; } r; r.i[0] = x; r.i[1] = y;
    return r.d;
}

__device__ __forceinline__ double bcast0_f64(double v) {
    union { double d; int i[2]; } u; u.d = v;
    int x = __builtin_amdgcn_readfirstlane(u.i[0]);
    int y = __builtin_amdgcn_readfirstlane(u.i[1]);
    union { int i[2]; double d; } r; r.i[0] = x; r.i[1] = y;
    return r.d;
}

// ---- inline-asm load pipeline primitives ----
// One divergent dword load: SGPR-pair base + per-lane 32-bit voffset +
// literal instruction offset. volatile => issue order is fixed.
#define GLOAD(dst, voff, base, OFFSTR)                              \
    asm volatile("global_load_dword %0, %1, %2 offset:" OFFSTR      \
                 : "=v"(dst) : "v"(voff), "s"(base) : "memory")

#define VM8  do { asm volatile("s_waitcnt vmcnt(8)" ::: "memory");  \
                  __builtin_amdgcn_sched_barrier(0); } while (0)
#define VM0  do { asm volatile("s_waitcnt vmcnt(0)" ::: "memory");  \
                  __builtin_amdgcn_sched_barrier(0); } while (0)

// forward: slots at rows base+0..+7  (offsets +512*s)
#define FISSUE(buf, voff) {                 \
    GLOAD(buf[0], voff, yp, "0");           \
    GLOAD(buf[1], voff, yp, "512");         \
    GLOAD(buf[2], voff, yp, "1024");        \
    GLOAD(buf[3], voff, yp, "1536");        \
    GLOAD(buf[4], voff, yp, "2048");        \
    GLOAD(buf[5], voff, yp, "2560");        \
    GLOAD(buf[6], voff, yp, "3072");        \
    GLOAD(buf[7], voff, yp, "3584"); }

// backward: slots at rows base-0..-7 (offsets -512*s)
#define BISSUE(buf, voff) {                 \
    GLOAD(buf[0], voff, yp, "0");           \
    GLOAD(buf[1], voff, yp, "-512");        \
    GLOAD(buf[2], voff, yp, "-1024");       \
    GLOAD(buf[3], voff, yp, "-1536");       \
    GLOAD(buf[4], voff, yp, "-2048");       \
    GLOAD(buf[5], voff, yp, "-2560");       \
    GLOAD(buf[6], voff, yp, "-3072");       \
    GLOAD(buf[7], voff, yp, "-3584"); }

__global__ __launch_bounds__(128) void ctc_loss_kernel(
    const int* __restrict__ y_true,   // [B, L] int32
    const float* __restrict__ y_pred, // [B, T, C] float32
    float* __restrict__ out)          // [B, 1] float32
{
    __shared__ double sA[64];   // beta a  (beta[2i+1]; beta[0] in sA[32])
    __shared__ double sB[64];   // beta bb (beta[2i+2])

    const int b = blockIdx.x;
    const int tid = threadIdx.x;
    const int lane = tid & 63;
    const int wave = tid >> 6;

    const float* yp = y_pred + (size_t)b * CTC_T * CTC_C;

    // per-lane label: lanes 0..31 -> y_true, others -> blank
    int lbl = CTC_BLANK;
    if (lane < CTC_L) lbl = y_true[b * CTC_L + lane];
    const int col_a = (lane < 32) ? lbl : CTC_BLANK;   // own gather column
    const bool is32 = (lane == 32);

    double lo = 0.0, hi = 0.0;   // fwd result (wave 0)

    if (wave == 0) {
        // ================= forward chain: t = 1..127 =================
        double skip = 0.0;
        if (lane >= 1 && lane < CTC_L) {
            if (y_true[b * CTC_L + lane - 1] != lbl) skip = 1.0;
        }
        // init (t = 0 row) — plain loads, complete before pipeline start
        if (lane == 0) {
            lo = (double)((yp[CTC_BLANK] + CTC_EPS) * 128.0f);  // alpha[0]
            hi = (double)((yp[lbl] + CTC_EPS) * 128.0f);        // alpha[1]
        }

#define FSTEP(Lt) {                                                         \
        float vtf = ((Lt) + CTC_EPS) * 128.0f;                              \
        float pbf = __int_as_float(                                         \
            __builtin_amdgcn_readlane(__float_as_int(vtf), 32));            \
        float pvf = (lane < 32) ? vtf : 0.0f;                               \
        double ph = dpp_shr1_f64(hi);                                       \
        double nl = (lo + ph) * (double)pbf;                                \
        double nh = (hi + lo + skip * ph) * (double)pvf;                    \
        lo = nl; hi = nh; }

        float A[8], Bv[8];
        int voffA = 1 * 512 + col_a * 4;          // group 0: rows 1..8
        int voffB = 9 * 512 + col_a * 4;          // group 1: rows 9..16
        FISSUE(A, voffA);  voffA += 8192;          // next A group: +16 rows
        FISSUE(Bv, voffB); voffB += 8192;
        for (int g = 0; g < 14; g += 2) {
            VM8;  // A's 8 done, B's 8 in flight
            FSTEP(A[0]); FSTEP(A[1]); FSTEP(A[2]); FSTEP(A[3]);
            FSTEP(A[4]); FSTEP(A[5]); FSTEP(A[6]); FSTEP(A[7]);
            FISSUE(A, voffA); voffA += 8192;
            VM8;
            FSTEP(Bv[0]); FSTEP(Bv[1]); FSTEP(Bv[2]); FSTEP(Bv[3]);
            FSTEP(Bv[4]); FSTEP(Bv[5]); FSTEP(Bv[6]); FSTEP(Bv[7]);
            FISSUE(Bv, voffB); voffB += 8192;
        }
        // tail: group 14 (k=112..119), group 15 (k=120..126; slot 7 dead)
        VM8;
        FSTEP(A[0]); FSTEP(A[1]); FSTEP(A[2]); FSTEP(A[3]);
        FSTEP(A[4]); FSTEP(A[5]); FSTEP(A[6]); FSTEP(A[7]);
        VM0;
        FSTEP(Bv[0]); FSTEP(Bv[1]); FSTEP(Bv[2]); FSTEP(Bv[3]);
        FSTEP(Bv[4]); FSTEP(Bv[5]); FSTEP(Bv[6]);
#undef FSTEP
    } else {
        // ================= backward chain: t = 255..128 ==============
        double skipn = 0.0;
        if (lane <= 30) {
            if (y_true[b * CTC_L + lane + 1] != lbl) skipn = 1.0;
        } else if (lane == 32) {
            skipn = 1.0;   // reuse v-term as the 0 -> 1 transition
        }
        double a = 0.0, bb = 0.0;
        if (lane == 31) { a = 1.0; bb = 1.0; }  // beta_255[63] = [64] = 1

#define BSTEP(Lt) {                                                         \
        float vta = ((Lt) + CTC_EPS) * 128.0f;                              \
        float pbbb = __int_as_float(                                        \
            __builtin_amdgcn_readlane(__float_as_int(vta), 63));            \
        float sh = __int_as_float(__builtin_amdgcn_update_dpp(              \
            0, __float_as_int(vta), DPP_WAVE_SHL1, 0xF, 0xF, true));        \
        float f0 = __int_as_float(                                          \
            __builtin_amdgcn_readfirstlane(__float_as_int(vta)));           \
        float pa1f = (lane == 31) ? 0.0f : (is32 ? f0 : sh);                \
        float paf  = vta;                                                   \
        float pbbf = is32 ? 0.0f : pbbb;                                    \
        double a1s = dpp_shl1_f64(a);                                       \
        double a1  = is32 ? bcast0_f64(a) : a1s;                            \
        double v  = (double)pa1f * a1;                                      \
        double u  = (double)pbbf * bb;                                      \
        double nb = u + v;                                                  \
        double na = fma((double)paf, a, fma(skipn, v, u));                  \
        a = na; bb = nb; }

        float A[8], Bv[8];
        int voffA = 255 * 512 + col_a * 4;        // group 0: rows 255..248
        int voffB = 247 * 512 + col_a * 4;        // group 1: rows 247..240
        BISSUE(A, voffA);  voffA -= 8192;
        BISSUE(Bv, voffB); voffB -= 8192;
        for (int g = 0; g < 14; g += 2) {
            VM8;
            BSTEP(A[0]); BSTEP(A[1]); BSTEP(A[2]); BSTEP(A[3]);
            BSTEP(A[4]); BSTEP(A[5]); BSTEP(A[6]); BSTEP(A[7]);
            BISSUE(A, voffA); voffA -= 8192;
            VM8;
            BSTEP(Bv[0]); BSTEP(Bv[1]); BSTEP(Bv[2]); BSTEP(Bv[3]);
            BSTEP(Bv[4]); BSTEP(Bv[5]); BSTEP(Bv[6]); BSTEP(Bv[7]);
            BISSUE(Bv, voffB); voffB -= 8192;
        }
        // tail: group 14 (rows 143..136), group 15 (rows 135..128) — full 8s
        VM8;
        BSTEP(A[0]); BSTEP(A[1]); BSTEP(A[2]); BSTEP(A[3]);
        BSTEP(A[4]); BSTEP(A[5]); BSTEP(A[6]); BSTEP(A[7]);
        VM0;
        BSTEP(Bv[0]); BSTEP(Bv[1]); BSTEP(Bv[2]); BSTEP(Bv[3]);
        BSTEP(Bv[4]); BSTEP(Bv[5]); BSTEP(Bv[6]); BSTEP(Bv[7]);
#undef BSTEP

        sA[lane] = a;
        sB[lane] = bb;
    }

    __syncthreads();

    if (wave == 0) {
        // ---- combine: P = sum_s alpha_127[s] * beta_127[s] ----
        // beta[2i]: i=0 -> beta[0] = sA[32]; i>=1 -> bb_{i-1} = sB[i-1]
        double aown = sA[lane];
        double beB  = sB[(lane + 63) & 63];
        double be   = (lane == 0) ? sA[32] : beB;
        double partial = (lane <= 32) ? (lo * be + hi * aown) : 0.0;
        #pragma unroll
        for (int off = 32; off >= 1; off >>= 1)
            partial += __shfl_down(partial, off);
        if (lane == 0) {
            out[b] = (float)(1242.1197475634219 - log(partial)); // 256*ln(128)
        }
    }
}

extern "C" void kernel_launch(void* const* d_in, const int* in_sizes, int n_in,
                              void* d_out, int out_size, void* d_ws, size_t ws_size,
                              hipStream_t stream) {
    const int*   y_true = (const int*)d_in[0];
    const float* y_pred = (const float*)d_in[1];
    float*       out    = (float*)d_out;

    ctc_loss_kernel<<<CTC_B, 128, 0, stream>>>(y_true, y_pred, out);
}